// Round 4
// baseline (7000.603 us; speedup 1.0000x reference)
//
#include <hip/hip_runtime.h>
#include <math.h>
#include <stdint.h>

// ---------------- problem constants ----------------
#define TOK   512
#define EMB   768
#define QKVD  2304
#define NHEAD 12
#define HD    64
#define MLPD  3072
#define SUBA  128

// ---------------- ws layout (bytes) ----------------
#define OFF_QKV      0ull
#define OFF_SCORES   9437184ull
#define OFF_CTX      22020096ull
#define OFF_H1PRE    25165824ull
#define OFF_H1       26738688ull
#define OFF_M1       28311552ull
#define OFF_X2       34603008ull
#define OFF_M2       40894464ull
#define OFF_DQ1      42467328ull
#define OFF_DQ2      42504192ull
#define OFF_SCAL     42651648ull
#define OFF_NOISE1   42651712ull
#define OFF_NOISE2   80400448ull
#define OFF_SUMXB1   118149184ull
#define OFF_SUMXB2   118186048ull
#define OFF_WDEC1    118333504ull
#define OFF_WDEC2    120692800ull
#define OFF_XQT1     123052096ull
#define OFF_XQT2     123445312ull
#define WS_NEEDED    125018176ull

// scalar slots (doubles as ull bit patterns, all non-negative)
// 0 wmax1, 1 wmax2, 2 xmax1, 3 ymax1, 4 dmax1, 5 xmax2, 6 ymax2, 7 dmax2

// ---------------- helpers ----------------
__device__ __forceinline__ void blockMaxAtomic(double v, unsigned long long* slot, double* red){
  int tid = threadIdx.x;
  red[tid] = v; __syncthreads();
  for (int st = 128; st > 0; st >>= 1){
    if (tid < st){ double o = red[tid+st]; if (o > red[tid]) red[tid] = o; }
    __syncthreads();
  }
  if (tid == 0) atomicMax(slot, (unsigned long long)__double_as_longlong(red[0]));
}

__device__ __forceinline__ double readSlot(const unsigned long long* s){
  return __longlong_as_double((long long)(*s));
}

// ---------------- XLA CPU f32 exp (Eigen pexp_float, FMA path) ----------------
__device__ __forceinline__ float xla_exp_f32(float _x){
  float x = fminf(_x, 88.3762626647950f);
  x = fmaxf(x, -88.3762626647949f);
  float m = floorf(fmaf(x, 1.44269504088896341f, 0.5f));
  float r = fmaf(m, -0.6931471805599453f, x);          // FMA path: single step
  float r2 = __fmul_rn(r, r);
  float r3 = __fmul_rn(r2, r);
  float y  = fmaf(1.9875691500e-4f, r, 1.3981999507e-3f);
  float y1 = fmaf(4.1665795894e-2f, r, 1.6666665459e-1f);
  float y2 = __fadd_rn(r, 1.0f);
  y  = fmaf(y, r, 8.3334519073e-3f);
  y1 = fmaf(y1, r, 5.0000001201e-1f);
  y  = fmaf(y, r3, y1);
  y  = fmaf(y, r2, y2);
  int mi = (int)m;
  float two_m = __uint_as_float((unsigned)((mi + 127) << 23));
  float res = __fmul_rn(y, two_m);
  return fmaxf(res, _x);
}

// ---------------- XLA CPU f32 erf (Eigen generic_fast_erf_float) ----------------
__device__ __forceinline__ float xla_erf_f32(float v){
  float x = fmaxf(fminf(v, 4.0f), -4.0f);
  float x2 = __fmul_rn(x, x);
  float p = fmaf(x2, -2.72614225801306e-10f, 2.77068142495902e-08f);
  p = fmaf(x2, p, -2.10102402082508e-06f);
  p = fmaf(x2, p, -5.69250639462346e-05f);
  p = fmaf(x2, p, -7.34990630326855e-04f);
  p = fmaf(x2, p, -2.95459980854025e-03f);
  p = fmaf(x2, p, -1.60960333262415e-02f);
  p = __fmul_rn(x, p);
  float q = fmaf(x2, -1.45660718464996e-05f, -2.13374055278905e-04f);
  q = fmaf(x2, q, -1.68282697438203e-03f);
  q = fmaf(x2, q, -7.37332916720468e-03f);
  q = fmaf(x2, q, -1.42647390514189e-02f);
  return __fdiv_rn(p, q);
}

// ---------------- threefry2x32 (JAX-exact) ----------------
__device__ __forceinline__ uint32_t rotl32(uint32_t x, int r){ return (x << r) | (x >> (32 - r)); }

__device__ __forceinline__ void threefry2x32(uint32_t k0, uint32_t k1,
                                             uint32_t x0, uint32_t x1,
                                             uint32_t& o0, uint32_t& o1){
  uint32_t ks2 = k0 ^ k1 ^ 0x1BD11BDAu;
  x0 += k0; x1 += k1;
#define TF_R(r) { x0 += x1; x1 = rotl32(x1, r); x1 ^= x0; }
  TF_R(13) TF_R(15) TF_R(26) TF_R(6)
  x0 += k1; x1 += ks2 + 1u;
  TF_R(17) TF_R(29) TF_R(16) TF_R(24)
  x0 += ks2; x1 += k0 + 2u;
  TF_R(13) TF_R(15) TF_R(26) TF_R(6)
  x0 += k0; x1 += k1 + 3u;
  TF_R(17) TF_R(29) TF_R(16) TF_R(24)
  x0 += k1; x1 += ks2 + 4u;
  TF_R(13) TF_R(15) TF_R(26) TF_R(6)
  x0 += ks2; x1 += k0 + 5u;
#undef TF_R
  o0 = x0; o1 = x1;
}

// bits -> VARI * sqrt(2) * erfinv(uniform(-1+eps, 1))  (XLA f32 op-for-op)
__device__ float bits_to_noise(uint32_t bits){
  uint32_t fb = (bits >> 9) | 0x3f800000u;
  float f = __uint_as_float(fb);
  f = __fadd_rn(f, -1.0f);                      // [0,1)
  const float lo = -0.99999994f;                // nextafter(-1,0)
  float u = __fadd_rn(__fmul_rn(f, 2.0f), lo);  // (hi-lo) rounds to exactly 2.0f
  u = fmaxf(lo, u);
  float x  = u;
  float xx = __fmul_rn(x, x);
  float nx = -xx;
  float l1p;
  if (fabsf(nx) < 1e-4f){
    l1p = __fmul_rn(__fadd_rn(__fmul_rn(-0.5f, nx), 1.0f), nx);
  } else {
    float u1 = __fadd_rn(nx, 1.0f);
    l1p = (float)log((double)u1);               // correctly-rounded f32 log
  }
  float w = -l1p;
  float p;
  if (w < 5.0f){
    w = __fadd_rn(w, -2.5f);
    p = 2.81022636e-08f;
    p = __fadd_rn(3.43273939e-07f, __fmul_rn(p, w));
    p = __fadd_rn(-3.5233877e-06f,  __fmul_rn(p, w));
    p = __fadd_rn(-4.39150654e-06f, __fmul_rn(p, w));
    p = __fadd_rn(0.00021858087f,   __fmul_rn(p, w));
    p = __fadd_rn(-0.00125372503f,  __fmul_rn(p, w));
    p = __fadd_rn(-0.00417768164f,  __fmul_rn(p, w));
    p = __fadd_rn(0.246640727f,     __fmul_rn(p, w));
    p = __fadd_rn(1.50140941f,      __fmul_rn(p, w));
  } else {
    float sw = __fsqrt_rn(w);
    w = __fadd_rn(sw, -3.0f);
    p = -0.000200214257f;
    p = __fadd_rn(0.000100950558f, __fmul_rn(p, w));
    p = __fadd_rn(0.00134934322f,  __fmul_rn(p, w));
    p = __fadd_rn(-0.00367342844f, __fmul_rn(p, w));
    p = __fadd_rn(0.00573950773f,  __fmul_rn(p, w));
    p = __fadd_rn(-0.0076224613f,  __fmul_rn(p, w));
    p = __fadd_rn(0.00943887047f,  __fmul_rn(p, w));
    p = __fadd_rn(1.00167406f,     __fmul_rn(p, w));
    p = __fadd_rn(2.83297682f,     __fmul_rn(p, w));
  }
  float ei  = __fmul_rn(p, x);
  float nrm = __fmul_rn(1.41421354f, ei);
  return __fmul_rn(0.02f, nrm);
}

// ---------------- reductions ----------------
__global__ void absmax_f32_k(const float* p, int n, unsigned long long* slot){
  __shared__ double red[256];
  double m = 0.0;
  for (int i = blockIdx.x*256 + threadIdx.x; i < n; i += gridDim.x*256){
    double v = fabs((double)p[i]); if (v > m) m = v;
  }
  blockMaxAtomic(m, slot, red);
}

// ---------------- weight preprocessing ----------------
// partitionable threefry: block (0, i), output o0 ^ o1
__global__ void noise_gen_k(uint32_t k0, uint32_t k1, unsigned int n, float* noise){
  unsigned int i = blockIdx.x*256u + threadIdx.x;
  if (i >= n) return;
  uint32_t o0, o1;
  threefry2x32(k0, k1, 0u, i, o0, o1);
  noise[i] = bits_to_noise(o0 ^ o1);
}

// Wdec = round_f32(((W/wmax + 1) * 0.5) * 15)
__global__ void wdec_gen_k(const float* W, int nW, const unsigned long long* wmax_slot,
                           unsigned char* Wdec){
  int i = blockIdx.x*256 + threadIdx.x;
  if (i >= nW) return;
  float wmax = (float)readSlot(wmax_slot);
  float d = __fdiv_rn(W[i], wmax);
  d = __fadd_rn(d, 1.0f);
  d = __fmul_rn(d, 0.5f);
  d = __fmul_rn(d, 15.0f);
  Wdec[i] = (unsigned char)(int)rintf(d);
}

// ---------------- attention (f32, sequential-K fma chains) ----------------
__global__ __launch_bounds__(256) void qkv_gemm_k(const float* x, const float* w, const float* b, float* qkv){
  __shared__ float xt[8][EMB];
  int j  = blockIdx.x*256 + threadIdx.x;
  int t0 = blockIdx.y*8;
  for (int v = threadIdx.x; v < 8*EMB; v += 256){
    int tt = v / EMB, e = v % EMB;
    xt[tt][e] = x[(size_t)(t0+tt)*EMB + e];
  }
  __syncthreads();
  float acc[8] = {0,0,0,0,0,0,0,0};
  const float* wr = w + (size_t)j*EMB;
  for (int e = 0; e < EMB; ++e){
    float wv = wr[e];
#pragma unroll
    for (int tt = 0; tt < 8; ++tt) acc[tt] = fmaf(xt[tt][e], wv, acc[tt]);
  }
  float bv = b[j];
  for (int tt = 0; tt < 8; ++tt)
    qkv[(size_t)(t0+tt)*QKVD + j] = __fadd_rn(acc[tt], bv);
}

__global__ __launch_bounds__(256) void attn_scores_k(const float* qkv, float* sc){
  __shared__ float kt[32][HD+1];
  int nh = blockIdx.x;
  int n  = nh / NHEAD, h = nh % NHEAD;
  int m0 = blockIdx.y * 32;
  int l  = threadIdx.x;
  for (int v = threadIdx.x; v < 32*HD; v += 256){
    int mm = v / HD, d = v % HD;
    kt[mm][d] = qkv[(size_t)((m0+mm)*2 + n)*QKVD + EMB + h*HD + d];
  }
  __syncthreads();
  float acc[32];
#pragma unroll
  for (int mm = 0; mm < 32; ++mm) acc[mm] = 0.0f;
  const float* qrow = qkv + (size_t)(l*2 + n)*QKVD + h*HD;
  for (int d = 0; d < HD; ++d){
    float qv = qrow[d];
#pragma unroll
    for (int mm = 0; mm < 32; ++mm) acc[mm] = fmaf(qv, kt[mm][d], acc[mm]);
  }
  float* srow = sc + ((size_t)nh*256 + l)*256 + m0;
#pragma unroll
  for (int mm = 0; mm < 32; ++mm) srow[mm] = __fdiv_rn(acc[mm], 8.0f);
}

// one thread per row: max (exact), exp (XLA), sequential sum, divide
__global__ void softmax_rows_k(float* sc){
  int row = blockIdx.x*256 + threadIdx.x;
  if (row >= 24*256) return;
  float* p = sc + (size_t)row*256;
  float mx = p[0];
  for (int m = 1; m < 256; ++m) mx = fmaxf(mx, p[m]);
  for (int m = 0; m < 256; ++m) p[m] = xla_exp_f32(__fsub_rn(p[m], mx));
  float s = 0.0f;
  for (int m = 0; m < 256; ++m) s = __fadd_rn(s, p[m]);
  for (int m = 0; m < 256; ++m) p[m] = __fdiv_rn(p[m], s);
}

__global__ void attn_ctx_k(const float* sc, const float* qkv, float* ctx){
  int idx = blockIdx.x*256 + threadIdx.x;
  int t = idx / EMB, i = idx % EMB;
  int l = t / 2, n = t % 2, h = i / HD;
  const float* arow = sc + ((size_t)(n*NHEAD + h)*256 + l)*256;
  float acc = 0.0f;
  for (int m = 0; m < 256; ++m)
    acc = fmaf(arow[m], qkv[(size_t)(m*2 + n)*QKVD + 1536 + i], acc);
  ctx[(size_t)t*EMB + i] = acc;
}

__global__ __launch_bounds__(256) void outproj_res_k(const float* ctx, const float* w, const float* b,
                                                     const float* x, float* h1pre){
  __shared__ float ct[8][EMB];
  int e  = blockIdx.x*256 + threadIdx.x;
  int t0 = blockIdx.y*8;
  for (int v = threadIdx.x; v < 8*EMB; v += 256){
    int tt = v / EMB, i = v % EMB;
    ct[tt][i] = ctx[(size_t)(t0+tt)*EMB + i];
  }
  __syncthreads();
  float acc[8] = {0,0,0,0,0,0,0,0};
  const float* wr = w + (size_t)e*EMB;
  for (int i = 0; i < EMB; ++i){
    float wv = wr[i];
#pragma unroll
    for (int tt = 0; tt < 8; ++tt) acc[tt] = fmaf(ct[tt][i], wv, acc[tt]);
  }
  float bv = b[e];
  for (int tt = 0; tt < 8; ++tt){
    size_t t = t0 + tt;
    float af = __fadd_rn(acc[tt], bv);
    h1pre[t*EMB + e] = __fadd_rn(x[t*EMB + e], af);
  }
}

// layernorm: one thread per row, sequential sums (XLA reduce order)
__global__ void ln_rows_k(const float* in, const float* g, const float* b, float* out){
  int t = blockIdx.x*256 + threadIdx.x;
  if (t >= TOK) return;
  const float* p = in + (size_t)t*EMB;
  float s = 0.0f;
  for (int e = 0; e < EMB; ++e) s = __fadd_rn(s, p[e]);
  float mu = __fdiv_rn(s, 768.0f);
  float s2 = 0.0f;
  for (int e = 0; e < EMB; ++e){
    float d = __fsub_rn(p[e], mu);
    s2 = __fadd_rn(s2, __fmul_rn(d, d));
  }
  float var = __fdiv_rn(s2, 768.0f);
  float rs = __fdiv_rn(1.0f, __fsqrt_rn(__fadd_rn(var, 1e-5f)));
  for (int e = 0; e < EMB; ++e){
    float d = __fsub_rn(p[e], mu);
    out[(size_t)t*EMB + e] = __fadd_rn(__fmul_rn(__fmul_rn(d, rs), g[e]), b[e]);
  }
}

// final layernorm over f32 (h1+m2)
__global__ void final_ln_rows_k(const float* h1, const float* m2, const float* g, const float* b, float* out){
  int t = blockIdx.x*256 + threadIdx.x;
  if (t >= TOK) return;
  const float* p  = h1 + (size_t)t*EMB;
  const float* p2 = m2 + (size_t)t*EMB;
  float s = 0.0f;
  for (int e = 0; e < EMB; ++e) s = __fadd_rn(s, __fadd_rn(p[e], p2[e]));
  float mu = __fdiv_rn(s, 768.0f);
  float s2 = 0.0f;
  for (int e = 0; e < EMB; ++e){
    float d = __fsub_rn(__fadd_rn(p[e], p2[e]), mu);
    s2 = __fadd_rn(s2, __fmul_rn(d, d));
  }
  float var = __fdiv_rn(s2, 768.0f);
  float rs = __fdiv_rn(1.0f, __fsqrt_rn(__fadd_rn(var, 1e-5f)));
  for (int e = 0; e < EMB; ++e){
    float d = __fsub_rn(__fadd_rn(p[e], p2[e]), mu);
    out[(size_t)t*EMB + e] = __fadd_rn(__fmul_rn(__fmul_rn(d, rs), g[e]), b[e]);
  }
}

// ---------------- qlinear (strict f32) ----------------
__global__ void quantx_k(const float* val, const unsigned long long* xmax_slot, int Fin,
                         signed char* XqT){
  int idx = blockIdx.x*256 + threadIdx.x;
  if (idx >= TOK*Fin) return;
  int t = idx / Fin, i = idx % Fin;
  float xmax = (float)readSlot(xmax_slot);
  float u = __fmul_rn(__fdiv_rn(val[idx], xmax), 7.0f);
  XqT[(size_t)i*TOK + t] = (signed char)(int)rintf(u);
}

__global__ void sumxb_k(const signed char* XqT, int NC, int* sumxb, unsigned long long* dmax_slot){
  int idx = blockIdx.x*256 + threadIdx.x;
  if (idx >= TOK*NC) return;
  int t = idx / NC, c = idx % NC;
  int n0 = 0, n1 = 0, n2 = 0;
  for (int s = 0; s < SUBA; ++s){
    int q = XqT[(size_t)(c*SUBA + s)*TOK + t];
    int a = q < 0 ? -q : q;
    int sg = (q > 0) - (q < 0);
    n0 += (a & 1) * sg; n1 += ((a >> 1) & 1) * sg; n2 += ((a >> 2) & 1) * sg;
  }
  sumxb[idx*3 + 0] = n0; sumxb[idx*3 + 1] = n1; sumxb[idx*3 + 2] = n2;
  float d0 = fabsf(__fmul_rn(0.55f, (float)n0));
  float d1 = fabsf(__fmul_rn(0.55f, (float)n1));
  float d2 = fabsf(__fmul_rn(0.55f, (float)n2));
  float m = fmaxf(d0, fmaxf(d1, d2));
  atomicMax(dmax_slot, (unsigned long long)__double_as_longlong((double)m));
}

__global__ void dummyq_k(const int* sumxb, int nTot, const unsigned long long* dmax_slot, float* dq){
  int i = blockIdx.x*256 + threadIdx.x;
  if (i >= nTot) return;
  float dmax = (float)readSlot(dmax_slot);
  float step = __fdiv_rn(dmax, 31.0f);
  if (!(step > 0.0f)) step = 1.0f;
  float P = __fmul_rn(0.55f, (float)sumxb[i]);
  dq[i] = __fmul_rn(rintf(__fdiv_rn(P, step)), step);
}

__device__ __forceinline__ void load_cond(const unsigned char* Wdec, const float* noise,
                                          int o, int c, int Fin, float cond[SUBA][4]){
  for (int v = threadIdx.x; v < SUBA*4; v += 256){
    int s = v >> 2, k = v & 3;
    size_t i = (size_t)o*Fin + c*SUBA + s;
    float bit = (float)((Wdec[i] >> k) & 1);
    float nz = noise[i*4 + k];
    cond[s][k] = __fmul_rn(__fadd_rn(__fmul_rn(bit, 0.9f), 0.1f), __fadd_rn(1.0f, nz));
  }
}

// sequential s=0..127 f32 chain per (z,k); products exact (+-cond), fma==add
__device__ __forceinline__ void qlin_acc_tile(const signed char* XqT, int c, int t,
                                              const float cond[SUBA][4], float acc[3][4]){
#pragma unroll
  for (int z = 0; z < 3; ++z)
#pragma unroll
    for (int k = 0; k < 4; ++k) acc[z][k] = 0.0f;
  for (int s = 0; s < SUBA; ++s){
    int q = XqT[(size_t)(c*SUBA + s)*TOK + t];
    if (q){
      int a = q < 0 ? -q : q;
#pragma unroll
      for (int k = 0; k < 4; ++k){
        float cv = cond[s][k];
        float sv = (q < 0) ? -cv : cv;
        if (a & 1) acc[0][k] = __fadd_rn(acc[0][k], sv);
        if (a & 2) acc[1][k] = __fadd_rn(acc[1][k], sv);
        if (a & 4) acc[2][k] = __fadd_rn(acc[2][k], sv);
      }
    }
  }
}

__global__ __launch_bounds__(256) void qlin_pass1_k(const signed char* XqT, const unsigned char* Wdec,
                                                    const float* noise, int Fin, int NC,
                                                    unsigned long long* ymax_slot){
  __shared__ float condLDS[SUBA][4];
  __shared__ double red[256];
  int o = blockIdx.x;
  int t = blockIdx.y*256 + threadIdx.x;
  float lmax = 0.0f;
  for (int c = 0; c < NC; ++c){
    __syncthreads();
    load_cond(Wdec, noise, o, c, Fin, condLDS);
    __syncthreads();
    float acc[3][4];
    qlin_acc_tile(XqT, c, t, condLDS, acc);
#pragma unroll
    for (int z = 0; z < 3; ++z)
#pragma unroll
      for (int k = 0; k < 4; ++k){
        float v = fabsf(acc[z][k]); if (v > lmax) lmax = v;
      }
  }
  blockMaxAtomic((double)lmax, ymax_slot, red);
}

// pass2: ADC quantize f32; jax order: reduce over c FIRST per (z,k), then 12-term z-major dot
__global__ __launch_bounds__(256) void qlin_pass2_k(const signed char* XqT, const unsigned char* Wdec,
                                                    const float* noise, const float* dq, const float* bias,
                                                    int Fout, int Fin, int NC,
                                                    const unsigned long long* ymax_slot,
                                                    const unsigned long long* xmax_slot,
                                                    const unsigned long long* wmax_slot,
                                                    float* outM){
  __shared__ float condLDS[SUBA][4];
  int o = blockIdx.x;
  int t = blockIdx.y*256 + threadIdx.x;
  float ymax = (float)readSlot(ymax_slot);
  float step = __fdiv_rn(ymax, 31.0f);
  if (!(step > 0.0f)) step = 1.0f;
  float netsum[3][4];
#pragma unroll
  for (int z = 0; z < 3; ++z)
#pragma unroll
    for (int k = 0; k < 4; ++k) netsum[z][k] = 0.0f;
  for (int c = 0; c < NC; ++c){
    __syncthreads();
    load_cond(Wdec, noise, o, c, Fin, condLDS);
    __syncthreads();
    float acc[3][4];
    qlin_acc_tile(XqT, c, t, condLDS, acc);
#pragma unroll
    for (int z = 0; z < 3; ++z){
      float dqv = dq[((size_t)t*NC + c)*3 + z];
#pragma unroll
      for (int k = 0; k < 4; ++k){
        float pq  = __fmul_rn(rintf(__fdiv_rn(acc[z][k], step)), step);
        float net = __fsub_rn(pq, dqv);
        netsum[z][k] = __fadd_rn(netsum[z][k], net);
      }
    }
  }
  float tot = 0.0f;
#pragma unroll
  for (int z = 0; z < 3; ++z)
#pragma unroll
    for (int k = 0; k < 4; ++k)
      tot = __fadd_rn(tot, __fmul_rn(netsum[z][k], (float)(1 << (z + k))));
  float xmax = (float)readSlot(xmax_slot);
  float wmax = (float)readSlot(wmax_slot);
  float A = __fdiv_rn(xmax, 7.0f);
  float B = __fdiv_rn(__fmul_rn(2.0f, wmax), 13.5f);
  float outv = __fadd_rn(__fmul_rn(__fmul_rn(tot, A), B), bias[o]);
  outM[(size_t)t*Fout + o] = outv;
}

// gelu exact via XLA erf poly + absmax
__global__ void gelu_absmax_k(const float* m1, int n, float* x2, unsigned long long* xmax_slot){
  __shared__ double red[256];
  double m = 0.0;
  for (int i = blockIdx.x*256 + threadIdx.x; i < n; i += gridDim.x*256){
    float v = m1[i];
    float t1 = __fdiv_rn(v, 1.4142135623730951f);   // f32(np.sqrt(2))
    float e = xla_erf_f32(t1);
    float s = __fadd_rn(e, 1.0f);
    float g = __fdiv_rn(__fmul_rn(v, s), 2.0f);
    x2[i] = g;
    double a = fabs((double)g); if (a > m) m = a;
  }
  blockMaxAtomic(m, xmax_slot, red);
}

// ---------------- host launch ----------------
extern "C" void kernel_launch(void* const* d_in, const int* in_sizes, int n_in,
                              void* d_out, int out_size, void* d_ws, size_t ws_size,
                              hipStream_t stream){
  if (ws_size < WS_NEEDED) return;
  const float* x      = (const float*)d_in[0];
  const float* in_w   = (const float*)d_in[1];
  const float* in_b   = (const float*)d_in[2];
  const float* out_w  = (const float*)d_in[3];
  const float* out_b  = (const float*)d_in[4];
  const float* ln1_g  = (const float*)d_in[5];
  const float* ln1_b  = (const float*)d_in[6];
  const float* W1     = (const float*)d_in[7];
  const float* b1     = (const float*)d_in[8];
  const float* W2     = (const float*)d_in[9];
  const float* b2     = (const float*)d_in[10];
  const float* ln2_g  = (const float*)d_in[11];
  const float* ln2_b  = (const float*)d_in[12];

  char* ws = (char*)d_ws;
  float* qkv    = (float*)(ws + OFF_QKV);
  float* scores = (float*)(ws + OFF_SCORES);
  float* ctx    = (float*)(ws + OFF_CTX);
  float* h1pre  = (float*)(ws + OFF_H1PRE);
  float* h1     = (float*)(ws + OFF_H1);
  float* m1     = (float*)(ws + OFF_M1);
  float* x2     = (float*)(ws + OFF_X2);
  float* m2     = (float*)(ws + OFF_M2);
  float* dq1    = (float*)(ws + OFF_DQ1);
  float* dq2    = (float*)(ws + OFF_DQ2);
  unsigned long long* scal = (unsigned long long*)(ws + OFF_SCAL);
  float* noise1  = (float*)(ws + OFF_NOISE1);
  float* noise2  = (float*)(ws + OFF_NOISE2);
  int*   sumxb1  = (int*)(ws + OFF_SUMXB1);
  int*   sumxb2  = (int*)(ws + OFF_SUMXB2);
  unsigned char* wdec1 = (unsigned char*)(ws + OFF_WDEC1);
  unsigned char* wdec2 = (unsigned char*)(ws + OFF_WDEC2);
  signed char* xqt1 = (signed char*)(ws + OFF_XQT1);
  signed char* xqt2 = (signed char*)(ws + OFF_XQT2);

  hipMemsetAsync(scal, 0, 64, stream);

  // weight maxima (exact, order-independent)
  absmax_f32_k<<<1024,256,0,stream>>>(W1, MLPD*EMB, scal+0);
  absmax_f32_k<<<1024,256,0,stream>>>(W2, EMB*MLPD, scal+1);

  // partitionable threefry noise + f32 weight levels
  noise_gen_k<<<36864,256,0,stream>>>(0u, 1u, 9437184u, noise1);
  noise_gen_k<<<36864,256,0,stream>>>(0u, 2u, 9437184u, noise2);
  wdec_gen_k<<<9216,256,0,stream>>>(W1, MLPD*EMB, scal+0, wdec1);
  wdec_gen_k<<<9216,256,0,stream>>>(W2, EMB*MLPD, scal+1, wdec2);

  // attention (f32, XLA-faithful)
  qkv_gemm_k<<<dim3(9,64),256,0,stream>>>(x, in_w, in_b, qkv);
  attn_scores_k<<<dim3(24,8),256,0,stream>>>(qkv, scores);
  softmax_rows_k<<<24,256,0,stream>>>(scores);
  attn_ctx_k<<<1536,256,0,stream>>>(scores, qkv, ctx);
  outproj_res_k<<<dim3(3,64),256,0,stream>>>(ctx, out_w, out_b, x, h1pre);
  ln_rows_k<<<2,256,0,stream>>>(h1pre, ln1_g, ln1_b, h1);

  // qlinear 1 (768 -> 3072)
  absmax_f32_k<<<1024,256,0,stream>>>(h1, TOK*EMB, scal+2);
  quantx_k<<<(TOK*EMB+255)/256,256,0,stream>>>(h1, scal+2, EMB, xqt1);
  sumxb_k<<<(TOK*6+255)/256,256,0,stream>>>(xqt1, 6, sumxb1, scal+4);
  dummyq_k<<<(TOK*6*3+255)/256,256,0,stream>>>(sumxb1, TOK*6*3, scal+4, dq1);
  qlin_pass1_k<<<dim3(MLPD,2),256,0,stream>>>(xqt1, wdec1, noise1, EMB, 6, scal+3);
  qlin_pass2_k<<<dim3(MLPD,2),256,0,stream>>>(xqt1, wdec1, noise1, dq1, b1,
                                              MLPD, EMB, 6, scal+3, scal+2, scal+0, m1);

  // gelu + qlinear 2 (3072 -> 768)
  gelu_absmax_k<<<6144,256,0,stream>>>(m1, TOK*MLPD, x2, scal+5);
  quantx_k<<<(TOK*MLPD+255)/256,256,0,stream>>>(x2, scal+5, MLPD, xqt2);
  sumxb_k<<<(TOK*24+255)/256,256,0,stream>>>(xqt2, 24, sumxb2, scal+7);
  dummyq_k<<<(TOK*24*3+255)/256,256,0,stream>>>(sumxb2, TOK*24*3, scal+7, dq2);
  qlin_pass1_k<<<dim3(EMB,2),256,0,stream>>>(xqt2, wdec2, noise2, MLPD, 24, scal+6);
  qlin_pass2_k<<<dim3(EMB,2),256,0,stream>>>(xqt2, wdec2, noise2, dq2, b2,
                                             EMB, MLPD, 24, scal+6, scal+5, scal+1, m2);

  // final residual + layernorm -> f32 out
  final_ln_rows_k<<<2,256,0,stream>>>(h1, m2, ln2_g, ln2_b, (float*)d_out);
}

// Round 5
// 3156.595 us; speedup vs baseline: 2.2178x; 2.2178x over previous
//
#include <hip/hip_runtime.h>
#include <math.h>
#include <stdint.h>

// ---------------- problem constants ----------------
#define TOK   512
#define EMB   768
#define QKVD  2304
#define NHEAD 12
#define HD    64
#define MLPD  3072
#define SUBA  128

// ---------------- ws layout (bytes) ----------------
#define OFF_QKV      0ull
#define OFF_SCORES   9437184ull
#define OFF_CTX      22020096ull
#define OFF_H1PRE    25165824ull
#define OFF_H1       26738688ull
#define OFF_M1       28311552ull
#define OFF_X2       34603008ull
#define OFF_M2       40894464ull
#define OFF_DQ1      42467328ull
#define OFF_DQ2      42504192ull
#define OFF_SCAL     42651648ull
#define OFF_NOISE1   42651712ull
#define OFF_NOISE2   80400448ull
#define OFF_SUMXB1   118149184ull
#define OFF_SUMXB2   118186048ull
#define OFF_WDEC1    118333504ull
#define OFF_WDEC2    120692800ull
#define OFF_XQT1     123052096ull
#define OFF_XQT2     123445312ull
#define WS_NEEDED    125018176ull

// scalar slots: 0 wmax1, 1 wmax2, 2 xmax1, 3 ymax1, 4 dmax1, 5 xmax2, 6 ymax2, 7 dmax2

// ---------------- helpers ----------------
__device__ __forceinline__ void blockMaxAtomic(double v, unsigned long long* slot, double* red){
  int tid = threadIdx.x;
  red[tid] = v; __syncthreads();
  for (int st = 128; st > 0; st >>= 1){
    if (tid < st){ double o = red[tid+st]; if (o > red[tid]) red[tid] = o; }
    __syncthreads();
  }
  if (tid == 0) atomicMax(slot, (unsigned long long)__double_as_longlong(red[0]));
}

__device__ __forceinline__ double readSlot(const unsigned long long* s){
  return __longlong_as_double((long long)(*s));
}

// ---------------- XLA CPU f32 exp (Eigen pexp_float, FMA path) ----------------
__device__ __forceinline__ float xla_exp_f32(float _x){
  float x = fminf(_x, 88.3762626647950f);
  x = fmaxf(x, -88.3762626647949f);
  float m = floorf(fmaf(x, 1.44269504088896341f, 0.5f));
  float r = fmaf(m, -0.6931471805599453f, x);
  float r2 = __fmul_rn(r, r);
  float r3 = __fmul_rn(r2, r);
  float y  = fmaf(1.9875691500e-4f, r, 1.3981999507e-3f);
  float y1 = fmaf(4.1665795894e-2f, r, 1.6666665459e-1f);
  float y2 = __fadd_rn(r, 1.0f);
  y  = fmaf(y, r, 8.3334519073e-3f);
  y1 = fmaf(y1, r, 5.0000001201e-1f);
  y  = fmaf(y, r3, y1);
  y  = fmaf(y, r2, y2);
  int mi = (int)m;
  float two_m = __uint_as_float((unsigned)((mi + 127) << 23));
  float res = __fmul_rn(y, two_m);
  return fmaxf(res, _x);
}

// ---------------- XLA CPU f32 erf (Eigen generic_fast_erf_float) ----------------
__device__ __forceinline__ float xla_erf_f32(float v){
  float x = fmaxf(fminf(v, 4.0f), -4.0f);
  float x2 = __fmul_rn(x, x);
  float p = fmaf(x2, -2.72614225801306e-10f, 2.77068142495902e-08f);
  p = fmaf(x2, p, -2.10102402082508e-06f);
  p = fmaf(x2, p, -5.69250639462346e-05f);
  p = fmaf(x2, p, -7.34990630326855e-04f);
  p = fmaf(x2, p, -2.95459980854025e-03f);
  p = fmaf(x2, p, -1.60960333262415e-02f);
  p = __fmul_rn(x, p);
  float q = fmaf(x2, -1.45660718464996e-05f, -2.13374055278905e-04f);
  q = fmaf(x2, q, -1.68282697438203e-03f);
  q = fmaf(x2, q, -7.37332916720468e-03f);
  q = fmaf(x2, q, -1.42647390514189e-02f);
  return __fdiv_rn(p, q);
}

// ---------------- threefry2x32 (JAX-exact) ----------------
__device__ __forceinline__ uint32_t rotl32(uint32_t x, int r){ return (x << r) | (x >> (32 - r)); }

__device__ __forceinline__ void threefry2x32(uint32_t k0, uint32_t k1,
                                             uint32_t x0, uint32_t x1,
                                             uint32_t& o0, uint32_t& o1){
  uint32_t ks2 = k0 ^ k1 ^ 0x1BD11BDAu;
  x0 += k0; x1 += k1;
#define TF_R(r) { x0 += x1; x1 = rotl32(x1, r); x1 ^= x0; }
  TF_R(13) TF_R(15) TF_R(26) TF_R(6)
  x0 += k1; x1 += ks2 + 1u;
  TF_R(17) TF_R(29) TF_R(16) TF_R(24)
  x0 += ks2; x1 += k0 + 2u;
  TF_R(13) TF_R(15) TF_R(26) TF_R(6)
  x0 += k0; x1 += k1 + 3u;
  TF_R(17) TF_R(29) TF_R(16) TF_R(24)
  x0 += k1; x1 += ks2 + 4u;
  TF_R(13) TF_R(15) TF_R(26) TF_R(6)
  x0 += ks2; x1 += k0 + 5u;
#undef TF_R
  o0 = x0; o1 = x1;
}

// bits -> VARI * sqrt(2) * erfinv(uniform(-1+eps, 1))  (XLA f32 op-for-op)
__device__ float bits_to_noise(uint32_t bits){
  uint32_t fb = (bits >> 9) | 0x3f800000u;
  float f = __uint_as_float(fb);
  f = __fadd_rn(f, -1.0f);
  const float lo = -0.99999994f;
  float u = __fadd_rn(__fmul_rn(f, 2.0f), lo);
  u = fmaxf(lo, u);
  float x  = u;
  float xx = __fmul_rn(x, x);
  float nx = -xx;
  float l1p;
  if (fabsf(nx) < 1e-4f){
    l1p = __fmul_rn(__fadd_rn(__fmul_rn(-0.5f, nx), 1.0f), nx);
  } else {
    float u1 = __fadd_rn(nx, 1.0f);
    l1p = (float)log((double)u1);
  }
  float w = -l1p;
  float p;
  if (w < 5.0f){
    w = __fadd_rn(w, -2.5f);
    p = 2.81022636e-08f;
    p = __fadd_rn(3.43273939e-07f, __fmul_rn(p, w));
    p = __fadd_rn(-3.5233877e-06f,  __fmul_rn(p, w));
    p = __fadd_rn(-4.39150654e-06f, __fmul_rn(p, w));
    p = __fadd_rn(0.00021858087f,   __fmul_rn(p, w));
    p = __fadd_rn(-0.00125372503f,  __fmul_rn(p, w));
    p = __fadd_rn(-0.00417768164f,  __fmul_rn(p, w));
    p = __fadd_rn(0.246640727f,     __fmul_rn(p, w));
    p = __fadd_rn(1.50140941f,      __fmul_rn(p, w));
  } else {
    float sw = __fsqrt_rn(w);
    w = __fadd_rn(sw, -3.0f);
    p = -0.000200214257f;
    p = __fadd_rn(0.000100950558f, __fmul_rn(p, w));
    p = __fadd_rn(0.00134934322f,  __fmul_rn(p, w));
    p = __fadd_rn(-0.00367342844f, __fmul_rn(p, w));
    p = __fadd_rn(0.00573950773f,  __fmul_rn(p, w));
    p = __fadd_rn(-0.0076224613f,  __fmul_rn(p, w));
    p = __fadd_rn(0.00943887047f,  __fmul_rn(p, w));
    p = __fadd_rn(1.00167406f,     __fmul_rn(p, w));
    p = __fadd_rn(2.83297682f,     __fmul_rn(p, w));
  }
  float ei  = __fmul_rn(p, x);
  float nrm = __fmul_rn(1.41421354f, ei);
  return __fmul_rn(0.02f, nrm);
}

// ---------------- reductions ----------------
__global__ void absmax_f32_k(const float* p, int n, unsigned long long* slot){
  __shared__ double red[256];
  double m = 0.0;
  for (int i = blockIdx.x*256 + threadIdx.x; i < n; i += gridDim.x*256){
    double v = fabs((double)p[i]); if (v > m) m = v;
  }
  blockMaxAtomic(m, slot, red);
}

// ---------------- weight preprocessing ----------------
__global__ void noise_gen_k(uint32_t k0, uint32_t k1, unsigned int n, float* noise){
  unsigned int i = blockIdx.x*256u + threadIdx.x;
  if (i >= n) return;
  uint32_t o0, o1;
  threefry2x32(k0, k1, 0u, i, o0, o1);
  noise[i] = bits_to_noise(o0 ^ o1);
}

__global__ void wdec_gen_k(const float* W, int nW, const unsigned long long* wmax_slot,
                           unsigned char* Wdec){
  int i = blockIdx.x*256 + threadIdx.x;
  if (i >= nW) return;
  float wmax = (float)readSlot(wmax_slot);
  float d = __fdiv_rn(W[i], wmax);
  d = __fadd_rn(d, 1.0f);
  d = __fmul_rn(d, 0.5f);
  d = __fmul_rn(d, 15.0f);
  Wdec[i] = (unsigned char)(int)rintf(d);
}

// ---------------- attention (f32, sequential-K fma chains) ----------------
__global__ __launch_bounds__(256) void qkv_gemm_k(const float* x, const float* w, const float* b, float* qkv){
  __shared__ float xt[8][EMB];
  int j  = blockIdx.x*256 + threadIdx.x;
  int t0 = blockIdx.y*8;
  for (int v = threadIdx.x; v < 8*EMB; v += 256){
    int tt = v / EMB, e = v % EMB;
    xt[tt][e] = x[(size_t)(t0+tt)*EMB + e];
  }
  __syncthreads();
  float acc[8] = {0,0,0,0,0,0,0,0};
  const float* wr = w + (size_t)j*EMB;
  for (int e = 0; e < EMB; ++e){
    float wv = wr[e];
#pragma unroll
    for (int tt = 0; tt < 8; ++tt) acc[tt] = fmaf(xt[tt][e], wv, acc[tt]);
  }
  float bv = b[j];
  for (int tt = 0; tt < 8; ++tt)
    qkv[(size_t)(t0+tt)*QKVD + j] = __fadd_rn(acc[tt], bv);
}

__global__ __launch_bounds__(256) void attn_scores_k(const float* qkv, float* sc){
  __shared__ float kt[32][HD+1];
  int nh = blockIdx.x;
  int n  = nh / NHEAD, h = nh % NHEAD;
  int m0 = blockIdx.y * 32;
  int l  = threadIdx.x;
  for (int v = threadIdx.x; v < 32*HD; v += 256){
    int mm = v / HD, d = v % HD;
    kt[mm][d] = qkv[(size_t)((m0+mm)*2 + n)*QKVD + EMB + h*HD + d];
  }
  __syncthreads();
  float acc[32];
#pragma unroll
  for (int mm = 0; mm < 32; ++mm) acc[mm] = 0.0f;
  const float* qrow = qkv + (size_t)(l*2 + n)*QKVD + h*HD;
  for (int d = 0; d < HD; ++d){
    float qv = qrow[d];
#pragma unroll
    for (int mm = 0; mm < 32; ++mm) acc[mm] = fmaf(qv, kt[mm][d], acc[mm]);
  }
  float* srow = sc + ((size_t)nh*256 + l)*256 + m0;
#pragma unroll
  for (int mm = 0; mm < 32; ++mm) srow[mm] = __fdiv_rn(acc[mm], 8.0f);
}

__global__ void softmax_rows_k(float* sc){
  int row = blockIdx.x*256 + threadIdx.x;
  if (row >= 24*256) return;
  float* p = sc + (size_t)row*256;
  float mx = p[0];
  for (int m = 1; m < 256; ++m) mx = fmaxf(mx, p[m]);
  for (int m = 0; m < 256; ++m) p[m] = xla_exp_f32(__fsub_rn(p[m], mx));
  float s = 0.0f;
  for (int m = 0; m < 256; ++m) s = __fadd_rn(s, p[m]);
  for (int m = 0; m < 256; ++m) p[m] = __fdiv_rn(p[m], s);
}

__global__ void attn_ctx_k(const float* sc, const float* qkv, float* ctx){
  int idx = blockIdx.x*256 + threadIdx.x;
  int t = idx / EMB, i = idx % EMB;
  int l = t / 2, n = t % 2, h = i / HD;
  const float* arow = sc + ((size_t)(n*NHEAD + h)*256 + l)*256;
  float acc = 0.0f;
  for (int m = 0; m < 256; ++m)
    acc = fmaf(arow[m], qkv[(size_t)(m*2 + n)*QKVD + 1536 + i], acc);
  ctx[(size_t)t*EMB + i] = acc;
}

__global__ __launch_bounds__(256) void outproj_res_k(const float* ctx, const float* w, const float* b,
                                                     const float* x, float* h1pre){
  __shared__ float ct[8][EMB];
  int e  = blockIdx.x*256 + threadIdx.x;
  int t0 = blockIdx.y*8;
  for (int v = threadIdx.x; v < 8*EMB; v += 256){
    int tt = v / EMB, i = v % EMB;
    ct[tt][i] = ctx[(size_t)(t0+tt)*EMB + i];
  }
  __syncthreads();
  float acc[8] = {0,0,0,0,0,0,0,0};
  const float* wr = w + (size_t)e*EMB;
  for (int i = 0; i < EMB; ++i){
    float wv = wr[i];
#pragma unroll
    for (int tt = 0; tt < 8; ++tt) acc[tt] = fmaf(ct[tt][i], wv, acc[tt]);
  }
  float bv = b[e];
  for (int tt = 0; tt < 8; ++tt){
    size_t t = t0 + tt;
    float af = __fadd_rn(acc[tt], bv);
    h1pre[t*EMB + e] = __fadd_rn(x[t*EMB + e], af);
  }
}

__global__ void ln_rows_k(const float* in, const float* g, const float* b, float* out){
  int t = blockIdx.x*256 + threadIdx.x;
  if (t >= TOK) return;
  const float* p = in + (size_t)t*EMB;
  float s = 0.0f;
  for (int e = 0; e < EMB; ++e) s = __fadd_rn(s, p[e]);
  float mu = __fdiv_rn(s, 768.0f);
  float s2 = 0.0f;
  for (int e = 0; e < EMB; ++e){
    float d = __fsub_rn(p[e], mu);
    s2 = __fadd_rn(s2, __fmul_rn(d, d));
  }
  float var = __fdiv_rn(s2, 768.0f);
  float rs = __fdiv_rn(1.0f, __fsqrt_rn(__fadd_rn(var, 1e-5f)));
  for (int e = 0; e < EMB; ++e){
    float d = __fsub_rn(p[e], mu);
    out[(size_t)t*EMB + e] = __fadd_rn(__fmul_rn(__fmul_rn(d, rs), g[e]), b[e]);
  }
}

// final layernorm; m2 is TRANSPOSED [e][t]
__global__ void final_ln_rows_k(const float* h1, const float* m2T, const float* g, const float* b, float* out){
  int t = blockIdx.x*256 + threadIdx.x;
  if (t >= TOK) return;
  const float* p = h1 + (size_t)t*EMB;
  float s = 0.0f;
  for (int e = 0; e < EMB; ++e) s = __fadd_rn(s, __fadd_rn(p[e], m2T[(size_t)e*TOK + t]));
  float mu = __fdiv_rn(s, 768.0f);
  float s2 = 0.0f;
  for (int e = 0; e < EMB; ++e){
    float d = __fsub_rn(__fadd_rn(p[e], m2T[(size_t)e*TOK + t]), mu);
    s2 = __fadd_rn(s2, __fmul_rn(d, d));
  }
  float var = __fdiv_rn(s2, 768.0f);
  float rs = __fdiv_rn(1.0f, __fsqrt_rn(__fadd_rn(var, 1e-5f)));
  for (int e = 0; e < EMB; ++e){
    float d = __fsub_rn(__fadd_rn(p[e], m2T[(size_t)e*TOK + t]), mu);
    out[(size_t)t*EMB + e] = __fadd_rn(__fmul_rn(__fmul_rn(d, rs), g[e]), b[e]);
  }
}

// ---------------- qlinear (strict f32, fma-restructured) ----------------
// layer-1 input h1 is [t][e]
__global__ void quantx_k(const float* val, const unsigned long long* xmax_slot, int Fin,
                         signed char* XqT){
  int idx = blockIdx.x*256 + threadIdx.x;
  if (idx >= TOK*Fin) return;
  int t = idx / Fin, i = idx % Fin;
  float xmax = (float)readSlot(xmax_slot);
  float u = __fmul_rn(__fdiv_rn(val[idx], xmax), 7.0f);
  XqT[(size_t)i*TOK + t] = (signed char)(int)rintf(u);
}

// layer-2 input x2 is already [i][t]
__global__ void quantxT_k(const float* valT, const unsigned long long* xmax_slot, int n,
                          signed char* XqT){
  int idx = blockIdx.x*256 + threadIdx.x;
  if (idx >= n) return;
  float xmax = (float)readSlot(xmax_slot);
  float u = __fmul_rn(__fdiv_rn(valT[idx], xmax), 7.0f);
  XqT[idx] = (signed char)(int)rintf(u);
}

__global__ void sumxb_k(const signed char* XqT, int NC, int* sumxb, unsigned long long* dmax_slot){
  int idx = blockIdx.x*256 + threadIdx.x;
  if (idx >= TOK*NC) return;
  int t = idx / NC, c = idx % NC;
  int n0 = 0, n1 = 0, n2 = 0;
  for (int s = 0; s < SUBA; ++s){
    int q = XqT[(size_t)(c*SUBA + s)*TOK + t];
    int a = q < 0 ? -q : q;
    int sg = (q > 0) - (q < 0);
    n0 += (a & 1) * sg; n1 += ((a >> 1) & 1) * sg; n2 += ((a >> 2) & 1) * sg;
  }
  sumxb[idx*3 + 0] = n0; sumxb[idx*3 + 1] = n1; sumxb[idx*3 + 2] = n2;
  float d0 = fabsf(__fmul_rn(0.55f, (float)n0));
  float d1 = fabsf(__fmul_rn(0.55f, (float)n1));
  float d2 = fabsf(__fmul_rn(0.55f, (float)n2));
  float m = fmaxf(d0, fmaxf(d1, d2));
  atomicMax(dmax_slot, (unsigned long long)__double_as_longlong((double)m));
}

// dqT layout: [c][z][t]
__global__ void dummyq_k(const int* sumxb, int NC, const unsigned long long* dmax_slot, float* dqT){
  int idx = blockIdx.x*256 + threadIdx.x;
  if (idx >= TOK*NC*3) return;
  int t = idx / (NC*3);
  int r = idx % (NC*3);
  int c = r / 3, z = r % 3;
  float dmax = (float)readSlot(dmax_slot);
  float step = __fdiv_rn(dmax, 31.0f);
  if (!(step > 0.0f)) step = 1.0f;
  float P = __fmul_rn(0.55f, (float)sumxb[idx]);
  dqT[((size_t)c*3 + z)*TOK + t] = __fmul_rn(rintf(__fdiv_rn(P, step)), step);
}

// cooperative stage of Xq tile (32KB) + cond tile for OTILE outputs
template<int OTILE>
__device__ __forceinline__ void qlin_stage(const signed char* XqT, const unsigned char* Wdec,
                                           const float* noise, int Fin, int c, int o0, int t0,
                                           signed char* xq, float (*cond)[SUBA][4]){
  const int tid = threadIdx.x;
  const uint32_t* src = (const uint32_t*)(XqT + (size_t)c*SUBA*TOK + t0);
  uint32_t* dst = (uint32_t*)xq;
  for (int j = tid; j < SUBA*64; j += 256){
    int s = j >> 6, dw = j & 63;
    dst[s*64 + dw] = src[s*128 + dw];     // [s][t] layout, t-tile of 256
  }
  for (int v = tid; v < OTILE*SUBA*4; v += 256){
    int o = v >> 9;
    int r = v & 511;
    int s = r >> 2, k = r & 3;
    size_t i = (size_t)(o0+o)*Fin + c*SUBA + s;
    float bit = (float)((Wdec[i] >> k) & 1);
    float nz  = noise[i*4 + k];
    cond[o][s][k] = __fmul_rn(__fadd_rn(__fmul_rn(bit, 0.9f), 0.1f), __fadd_rn(1.0f, nz));
  }
}

// branchless inner: acc[o][z*4+k] = fmaf(bz, cond[o][s][k], acc) -- bit-exact
// vs the sequential __fadd_rn chain (product exact in {-c,-0,+0,+c}; +-0 adds are no-ops)
template<int OTILE>
__device__ __forceinline__ void qlin_acc_c(const signed char* xq, const float (*cond)[SUBA][4],
                                           float (*acc)[12]){
  const int tid = threadIdx.x;
#pragma unroll
  for (int o = 0; o < OTILE; ++o)
#pragma unroll
    for (int r = 0; r < 12; ++r) acc[o][r] = 0.0f;
  for (int s = 0; s < SUBA; ++s){
    int q = xq[s*256 + tid];
    int a = q < 0 ? -q : q;
    int i0 = a & 1, i1 = (a >> 1) & 1, i2 = (a >> 2) & 1;
    if (q < 0){ i0 = -i0; i1 = -i1; i2 = -i2; }
    float b0 = (float)i0, b1 = (float)i1, b2 = (float)i2;
#pragma unroll
    for (int o = 0; o < OTILE; ++o){
      const float4 cv = *(const float4*)&cond[o][s][0];
      acc[o][0]  = fmaf(b0, cv.x, acc[o][0]);
      acc[o][1]  = fmaf(b0, cv.y, acc[o][1]);
      acc[o][2]  = fmaf(b0, cv.z, acc[o][2]);
      acc[o][3]  = fmaf(b0, cv.w, acc[o][3]);
      acc[o][4]  = fmaf(b1, cv.x, acc[o][4]);
      acc[o][5]  = fmaf(b1, cv.y, acc[o][5]);
      acc[o][6]  = fmaf(b1, cv.z, acc[o][6]);
      acc[o][7]  = fmaf(b1, cv.w, acc[o][7]);
      acc[o][8]  = fmaf(b2, cv.x, acc[o][8]);
      acc[o][9]  = fmaf(b2, cv.y, acc[o][9]);
      acc[o][10] = fmaf(b2, cv.z, acc[o][10]);
      acc[o][11] = fmaf(b2, cv.w, acc[o][11]);
    }
  }
}

template<int OTILE>
__global__ __launch_bounds__(256) void qlin_pass1_t(const signed char* XqT, const unsigned char* Wdec,
                                                    const float* noise, int Fin, int NC,
                                                    unsigned long long* ymax_slot){
  __shared__ signed char xq[SUBA*256];
  __shared__ float cond[OTILE][SUBA][4];
  __shared__ double red[256];
  const int o0 = blockIdx.x*OTILE;
  const int t0 = blockIdx.y*256;
  float acc[OTILE][12];
  float lmax = 0.0f;
  for (int c = 0; c < NC; ++c){
    __syncthreads();
    qlin_stage<OTILE>(XqT, Wdec, noise, Fin, c, o0, t0, xq, cond);
    __syncthreads();
    qlin_acc_c<OTILE>(xq, cond, acc);
#pragma unroll
    for (int o = 0; o < OTILE; ++o)
#pragma unroll
      for (int r = 0; r < 12; ++r) lmax = fmaxf(lmax, fabsf(acc[o][r]));
  }
  blockMaxAtomic((double)lmax, ymax_slot, red);
}

template<int OTILE>
__global__ __launch_bounds__(256) void qlin_pass2_t(const signed char* XqT, const unsigned char* Wdec,
                                                    const float* noise, const float* dqT, const float* bias,
                                                    int Fin, int NC,
                                                    const unsigned long long* ymax_slot,
                                                    const unsigned long long* xmax_slot,
                                                    const unsigned long long* wmax_slot,
                                                    float* outT){
  __shared__ signed char xq[SUBA*256];
  __shared__ float cond[OTILE][SUBA][4];
  const int o0 = blockIdx.x*OTILE;
  const int t0 = blockIdx.y*256;
  const int t  = t0 + threadIdx.x;
  float ymax = (float)readSlot(ymax_slot);
  float step = __fdiv_rn(ymax, 31.0f);
  if (!(step > 0.0f)) step = 1.0f;
  float acc[OTILE][12];
  float netsum[OTILE][12];
#pragma unroll
  for (int o = 0; o < OTILE; ++o)
#pragma unroll
    for (int r = 0; r < 12; ++r) netsum[o][r] = 0.0f;
  for (int c = 0; c < NC; ++c){
    __syncthreads();
    qlin_stage<OTILE>(XqT, Wdec, noise, Fin, c, o0, t0, xq, cond);
    __syncthreads();
    qlin_acc_c<OTILE>(xq, cond, acc);
    float dqv[3];
#pragma unroll
    for (int z = 0; z < 3; ++z) dqv[z] = dqT[((size_t)c*3 + z)*TOK + t];
#pragma unroll
    for (int o = 0; o < OTILE; ++o)
#pragma unroll
      for (int z = 0; z < 3; ++z)
#pragma unroll
        for (int k = 0; k < 4; ++k){
          float pq  = __fmul_rn(rintf(__fdiv_rn(acc[o][z*4+k], step)), step);
          float net = __fsub_rn(pq, dqv[z]);
          netsum[o][z*4+k] = __fadd_rn(netsum[o][z*4+k], net);
        }
  }
  float xmax = (float)readSlot(xmax_slot);
  float wmax = (float)readSlot(wmax_slot);
  float A = __fdiv_rn(xmax, 7.0f);
  float B = __fdiv_rn(__fmul_rn(2.0f, wmax), 13.5f);
#pragma unroll
  for (int o = 0; o < OTILE; ++o){
    float tot = 0.0f;
#pragma unroll
    for (int z = 0; z < 3; ++z)
#pragma unroll
      for (int k = 0; k < 4; ++k)
        tot = __fadd_rn(tot, __fmul_rn(netsum[o][z*4+k], (float)(1 << (z + k))));
    float outv = __fadd_rn(__fmul_rn(__fmul_rn(tot, A), B), bias[o0+o]);
    outT[(size_t)(o0+o)*TOK + t] = outv;     // transposed [o][t], coalesced
  }
}

// gelu exact via XLA erf poly + absmax (elementwise, layout-agnostic)
__global__ void gelu_absmax_k(const float* m1, int n, float* x2, unsigned long long* xmax_slot){
  __shared__ double red[256];
  double m = 0.0;
  for (int i = blockIdx.x*256 + threadIdx.x; i < n; i += gridDim.x*256){
    float v = m1[i];
    float t1 = __fdiv_rn(v, 1.4142135623730951f);
    float e = xla_erf_f32(t1);
    float s = __fadd_rn(e, 1.0f);
    float g = __fdiv_rn(__fmul_rn(v, s), 2.0f);
    x2[i] = g;
    double a = fabs((double)g); if (a > m) m = a;
  }
  blockMaxAtomic(m, xmax_slot, red);
}

// ---------------- host launch ----------------
extern "C" void kernel_launch(void* const* d_in, const int* in_sizes, int n_in,
                              void* d_out, int out_size, void* d_ws, size_t ws_size,
                              hipStream_t stream){
  if (ws_size < WS_NEEDED) return;
  const float* x      = (const float*)d_in[0];
  const float* in_w   = (const float*)d_in[1];
  const float* in_b   = (const float*)d_in[2];
  const float* out_w  = (const float*)d_in[3];
  const float* out_b  = (const float*)d_in[4];
  const float* ln1_g  = (const float*)d_in[5];
  const float* ln1_b  = (const float*)d_in[6];
  const float* W1     = (const float*)d_in[7];
  const float* b1     = (const float*)d_in[8];
  const float* W2     = (const float*)d_in[9];
  const float* b2     = (const float*)d_in[10];
  const float* ln2_g  = (const float*)d_in[11];
  const float* ln2_b  = (const float*)d_in[12];

  char* ws = (char*)d_ws;
  float* qkv    = (float*)(ws + OFF_QKV);
  float* scores = (float*)(ws + OFF_SCORES);
  float* ctx    = (float*)(ws + OFF_CTX);
  float* h1pre  = (float*)(ws + OFF_H1PRE);
  float* h1     = (float*)(ws + OFF_H1);
  float* m1     = (float*)(ws + OFF_M1);     // [MLPD][TOK] transposed
  float* x2     = (float*)(ws + OFF_X2);     // [MLPD][TOK]
  float* m2     = (float*)(ws + OFF_M2);     // [EMB][TOK]  transposed
  float* dq1    = (float*)(ws + OFF_DQ1);    // [6][3][TOK]
  float* dq2    = (float*)(ws + OFF_DQ2);    // [24][3][TOK]
  unsigned long long* scal = (unsigned long long*)(ws + OFF_SCAL);
  float* noise1  = (float*)(ws + OFF_NOISE1);
  float* noise2  = (float*)(ws + OFF_NOISE2);
  int*   sumxb1  = (int*)(ws + OFF_SUMXB1);
  int*   sumxb2  = (int*)(ws + OFF_SUMXB2);
  unsigned char* wdec1 = (unsigned char*)(ws + OFF_WDEC1);
  unsigned char* wdec2 = (unsigned char*)(ws + OFF_WDEC2);
  signed char* xqt1 = (signed char*)(ws + OFF_XQT1);
  signed char* xqt2 = (signed char*)(ws + OFF_XQT2);

  hipMemsetAsync(scal, 0, 64, stream);

  absmax_f32_k<<<1024,256,0,stream>>>(W1, MLPD*EMB, scal+0);
  absmax_f32_k<<<1024,256,0,stream>>>(W2, EMB*MLPD, scal+1);

  noise_gen_k<<<36864,256,0,stream>>>(0u, 1u, 9437184u, noise1);
  noise_gen_k<<<36864,256,0,stream>>>(0u, 2u, 9437184u, noise2);
  wdec_gen_k<<<9216,256,0,stream>>>(W1, MLPD*EMB, scal+0, wdec1);
  wdec_gen_k<<<9216,256,0,stream>>>(W2, EMB*MLPD, scal+1, wdec2);

  // attention (f32, XLA-faithful)
  qkv_gemm_k<<<dim3(9,64),256,0,stream>>>(x, in_w, in_b, qkv);
  attn_scores_k<<<dim3(24,8),256,0,stream>>>(qkv, scores);
  softmax_rows_k<<<24,256,0,stream>>>(scores);
  attn_ctx_k<<<1536,256,0,stream>>>(scores, qkv, ctx);
  outproj_res_k<<<dim3(3,64),256,0,stream>>>(ctx, out_w, out_b, x, h1pre);
  ln_rows_k<<<2,256,0,stream>>>(h1pre, ln1_g, ln1_b, h1);

  // qlinear 1 (768 -> 3072)
  absmax_f32_k<<<1024,256,0,stream>>>(h1, TOK*EMB, scal+2);
  quantx_k<<<(TOK*EMB+255)/256,256,0,stream>>>(h1, scal+2, EMB, xqt1);
  sumxb_k<<<(TOK*6+255)/256,256,0,stream>>>(xqt1, 6, sumxb1, scal+4);
  dummyq_k<<<(TOK*6*3+255)/256,256,0,stream>>>(sumxb1, 6, scal+4, dq1);
  qlin_pass1_t<8><<<dim3(MLPD/8,2),256,0,stream>>>(xqt1, wdec1, noise1, EMB, 6, scal+3);
  qlin_pass2_t<4><<<dim3(MLPD/4,2),256,0,stream>>>(xqt1, wdec1, noise1, dq1, b1,
                                                   EMB, 6, scal+3, scal+2, scal+0, m1);

  // gelu + qlinear 2 (3072 -> 768)
  gelu_absmax_k<<<6144,256,0,stream>>>(m1, TOK*MLPD, x2, scal+5);
  quantxT_k<<<(TOK*MLPD+255)/256,256,0,stream>>>(x2, scal+5, TOK*MLPD, xqt2);
  sumxb_k<<<(TOK*24+255)/256,256,0,stream>>>(xqt2, 24, sumxb2, scal+7);
  dummyq_k<<<(TOK*24*3+255)/256,256,0,stream>>>(sumxb2, 24, scal+7, dq2);
  qlin_pass1_t<4><<<dim3(EMB/4,2),256,0,stream>>>(xqt2, wdec2, noise2, MLPD, 24, scal+6);
  qlin_pass2_t<4><<<dim3(EMB/4,2),256,0,stream>>>(xqt2, wdec2, noise2, dq2, b2,
                                                  MLPD, 24, scal+6, scal+5, scal+1, m2);

  // final residual + layernorm -> f32 out
  final_ln_rows_k<<<2,256,0,stream>>>(h1, m2, ln2_g, ln2_b, (float*)d_out);
}

// Round 6
// 3149.486 us; speedup vs baseline: 2.2228x; 1.0023x over previous
//
#include <hip/hip_runtime.h>
#include <math.h>
#include <stdint.h>

// ---------------- problem constants ----------------
#define TOK   512
#define EMB   768
#define QKVD  2304
#define NHEAD 12
#define HD    64
#define MLPD  3072
#define SUBA  128

// ---------------- ws layout (bytes) ----------------
#define OFF_QKV      0ull
#define OFF_SCORES   9437184ull
#define OFF_CTX      22020096ull
#define OFF_H1PRE    25165824ull
#define OFF_H1       26738688ull
#define OFF_M1       28311552ull
#define OFF_X2       34603008ull
#define OFF_M2       40894464ull
#define OFF_DQ1      42467328ull
#define OFF_DQ2      42504192ull
#define OFF_SCAL     42651648ull
#define OFF_NOISE1   42651712ull
#define OFF_NOISE2   80400448ull
#define OFF_SUMXB1   118149184ull
#define OFF_SUMXB2   118186048ull
#define OFF_WDEC1    118333504ull
#define OFF_WDEC2    120692800ull
#define OFF_XQT1     123052096ull
#define OFF_XQT2     123445312ull
#define WS_NEEDED    125018176ull

// scalar slots: 0 wmax1, 1 wmax2, 2 xmax1, 3 ymax1, 4 dmax1, 5 xmax2, 6 ymax2, 7 dmax2

typedef float f32x2 __attribute__((ext_vector_type(2)));

// packed 2xf32 fma: two INDEPENDENT IEEE f32 fmas -> bit-exact vs two fmaf calls
__device__ __forceinline__ f32x2 pkfma(f32x2 a, f32x2 b, f32x2 c){
#if __has_builtin(__builtin_elementwise_fma)
  return __builtin_elementwise_fma(a, b, c);
#else
  f32x2 r; r.x = fmaf(a.x, b.x, c.x); r.y = fmaf(a.y, b.y, c.y); return r;
#endif
}

// ---------------- helpers ----------------
__device__ __forceinline__ void blockMaxAtomic(double v, unsigned long long* slot, double* red){
  int tid = threadIdx.x;
  red[tid] = v; __syncthreads();
  for (int st = 128; st > 0; st >>= 1){
    if (tid < st){ double o = red[tid+st]; if (o > red[tid]) red[tid] = o; }
    __syncthreads();
  }
  if (tid == 0) atomicMax(slot, (unsigned long long)__double_as_longlong(red[0]));
}

__device__ __forceinline__ double readSlot(const unsigned long long* s){
  return __longlong_as_double((long long)(*s));
}

// ---------------- XLA CPU f32 exp (Eigen pexp_float, FMA path) ----------------
__device__ __forceinline__ float xla_exp_f32(float _x){
  float x = fminf(_x, 88.3762626647950f);
  x = fmaxf(x, -88.3762626647949f);
  float m = floorf(fmaf(x, 1.44269504088896341f, 0.5f));
  float r = fmaf(m, -0.6931471805599453f, x);
  float r2 = __fmul_rn(r, r);
  float r3 = __fmul_rn(r2, r);
  float y  = fmaf(1.9875691500e-4f, r, 1.3981999507e-3f);
  float y1 = fmaf(4.1665795894e-2f, r, 1.6666665459e-1f);
  float y2 = __fadd_rn(r, 1.0f);
  y  = fmaf(y, r, 8.3334519073e-3f);
  y1 = fmaf(y1, r, 5.0000001201e-1f);
  y  = fmaf(y, r3, y1);
  y  = fmaf(y, r2, y2);
  int mi = (int)m;
  float two_m = __uint_as_float((unsigned)((mi + 127) << 23));
  float res = __fmul_rn(y, two_m);
  return fmaxf(res, _x);
}

// ---------------- XLA CPU f32 erf (Eigen generic_fast_erf_float) ----------------
__device__ __forceinline__ float xla_erf_f32(float v){
  float x = fmaxf(fminf(v, 4.0f), -4.0f);
  float x2 = __fmul_rn(x, x);
  float p = fmaf(x2, -2.72614225801306e-10f, 2.77068142495902e-08f);
  p = fmaf(x2, p, -2.10102402082508e-06f);
  p = fmaf(x2, p, -5.69250639462346e-05f);
  p = fmaf(x2, p, -7.34990630326855e-04f);
  p = fmaf(x2, p, -2.95459980854025e-03f);
  p = fmaf(x2, p, -1.60960333262415e-02f);
  p = __fmul_rn(x, p);
  float q = fmaf(x2, -1.45660718464996e-05f, -2.13374055278905e-04f);
  q = fmaf(x2, q, -1.68282697438203e-03f);
  q = fmaf(x2, q, -7.37332916720468e-03f);
  q = fmaf(x2, q, -1.42647390514189e-02f);
  return __fdiv_rn(p, q);
}

// ---------------- threefry2x32 (JAX-exact) ----------------
__device__ __forceinline__ uint32_t rotl32(uint32_t x, int r){ return (x << r) | (x >> (32 - r)); }

__device__ __forceinline__ void threefry2x32(uint32_t k0, uint32_t k1,
                                             uint32_t x0, uint32_t x1,
                                             uint32_t& o0, uint32_t& o1){
  uint32_t ks2 = k0 ^ k1 ^ 0x1BD11BDAu;
  x0 += k0; x1 += k1;
#define TF_R(r) { x0 += x1; x1 = rotl32(x1, r); x1 ^= x0; }
  TF_R(13) TF_R(15) TF_R(26) TF_R(6)
  x0 += k1; x1 += ks2 + 1u;
  TF_R(17) TF_R(29) TF_R(16) TF_R(24)
  x0 += ks2; x1 += k0 + 2u;
  TF_R(13) TF_R(15) TF_R(26) TF_R(6)
  x0 += k0; x1 += k1 + 3u;
  TF_R(17) TF_R(29) TF_R(16) TF_R(24)
  x0 += k1; x1 += ks2 + 4u;
  TF_R(13) TF_R(15) TF_R(26) TF_R(6)
  x0 += ks2; x1 += k0 + 5u;
#undef TF_R
  o0 = x0; o1 = x1;
}

__device__ float bits_to_noise(uint32_t bits){
  uint32_t fb = (bits >> 9) | 0x3f800000u;
  float f = __uint_as_float(fb);
  f = __fadd_rn(f, -1.0f);
  const float lo = -0.99999994f;
  float u = __fadd_rn(__fmul_rn(f, 2.0f), lo);
  u = fmaxf(lo, u);
  float x  = u;
  float xx = __fmul_rn(x, x);
  float nx = -xx;
  float l1p;
  if (fabsf(nx) < 1e-4f){
    l1p = __fmul_rn(__fadd_rn(__fmul_rn(-0.5f, nx), 1.0f), nx);
  } else {
    float u1 = __fadd_rn(nx, 1.0f);
    l1p = (float)log((double)u1);
  }
  float w = -l1p;
  float p;
  if (w < 5.0f){
    w = __fadd_rn(w, -2.5f);
    p = 2.81022636e-08f;
    p = __fadd_rn(3.43273939e-07f, __fmul_rn(p, w));
    p = __fadd_rn(-3.5233877e-06f,  __fmul_rn(p, w));
    p = __fadd_rn(-4.39150654e-06f, __fmul_rn(p, w));
    p = __fadd_rn(0.00021858087f,   __fmul_rn(p, w));
    p = __fadd_rn(-0.00125372503f,  __fmul_rn(p, w));
    p = __fadd_rn(-0.00417768164f,  __fmul_rn(p, w));
    p = __fadd_rn(0.246640727f,     __fmul_rn(p, w));
    p = __fadd_rn(1.50140941f,      __fmul_rn(p, w));
  } else {
    float sw = __fsqrt_rn(w);
    w = __fadd_rn(sw, -3.0f);
    p = -0.000200214257f;
    p = __fadd_rn(0.000100950558f, __fmul_rn(p, w));
    p = __fadd_rn(0.00134934322f,  __fmul_rn(p, w));
    p = __fadd_rn(-0.00367342844f, __fmul_rn(p, w));
    p = __fadd_rn(0.00573950773f,  __fmul_rn(p, w));
    p = __fadd_rn(-0.0076224613f,  __fmul_rn(p, w));
    p = __fadd_rn(0.00943887047f,  __fmul_rn(p, w));
    p = __fadd_rn(1.00167406f,     __fmul_rn(p, w));
    p = __fadd_rn(2.83297682f,     __fmul_rn(p, w));
  }
  float ei  = __fmul_rn(p, x);
  float nrm = __fmul_rn(1.41421354f, ei);
  return __fmul_rn(0.02f, nrm);
}

// ---------------- reductions ----------------
__global__ void absmax_f32_k(const float* p, int n, unsigned long long* slot){
  __shared__ double red[256];
  double m = 0.0;
  for (int i = blockIdx.x*256 + threadIdx.x; i < n; i += gridDim.x*256){
    double v = fabs((double)p[i]); if (v > m) m = v;
  }
  blockMaxAtomic(m, slot, red);
}

// ---------------- weight preprocessing ----------------
__global__ void noise_gen_k(uint32_t k0, uint32_t k1, unsigned int n, float* noise){
  unsigned int i = blockIdx.x*256u + threadIdx.x;
  if (i >= n) return;
  uint32_t o0, o1;
  threefry2x32(k0, k1, 0u, i, o0, o1);
  noise[i] = bits_to_noise(o0 ^ o1);
}

__global__ void wdec_gen_k(const float* W, int nW, const unsigned long long* wmax_slot,
                           unsigned char* Wdec){
  int i = blockIdx.x*256 + threadIdx.x;
  if (i >= nW) return;
  float wmax = (float)readSlot(wmax_slot);
  float d = __fdiv_rn(W[i], wmax);
  d = __fadd_rn(d, 1.0f);
  d = __fmul_rn(d, 0.5f);
  d = __fmul_rn(d, 15.0f);
  Wdec[i] = (unsigned char)(int)rintf(d);
}

// ---------------- fused row-major GEMM: out[t][j] = src[t][:]*w[j][:] + b[j] (+resid) ----------------
// 8 t's per block-row, 256 j's per block-col; per-output K-chain = e ascending (exact).
#define KTILE 32
__global__ __launch_bounds__(256) void gemm8_k(const float* src, const float* w, const float* bias,
                                               const float* resid, float* out, int N, int K){
  __shared__ float xt[EMB*8];             // [e][tt]
  __shared__ float wl[256*(KTILE+1)];
  const int tid = threadIdx.x;
  const int j  = blockIdx.x*256 + tid;
  const int t0 = blockIdx.y*8;
  for (int v = tid; v < K*8; v += 256){
    int e = v >> 3, tt = v & 7;
    xt[v] = src[(size_t)(t0+tt)*K + e];
  }
  f32x2 acc[4] = {{0.f,0.f},{0.f,0.f},{0.f,0.f},{0.f,0.f}};
  const int ntile = K / KTILE;
  for (int et = 0; et < ntile; ++et){
    __syncthreads();
    for (int v = tid; v < 256*KTILE; v += 256){
      int r = v >> 5, cc = v & 31;
      wl[r*(KTILE+1) + cc] = w[(size_t)(blockIdx.x*256 + r)*K + et*KTILE + cc];
    }
    __syncthreads();
    for (int ee = 0; ee < KTILE; ++ee){
      float wv = wl[tid*(KTILE+1) + ee];
      f32x2 wv2 = {wv, wv};
      const f32x2* xp = (const f32x2*)&xt[(et*KTILE + ee)*8];
#pragma unroll
      for (int q = 0; q < 4; ++q) acc[q] = pkfma(xp[q], wv2, acc[q]);
    }
  }
  float bv = bias[j];
#pragma unroll
  for (int q = 0; q < 4; ++q){
    float a0 = __fadd_rn(acc[q].x, bv);
    float a1 = __fadd_rn(acc[q].y, bv);
    size_t ta = (size_t)(t0 + q*2), tb = ta + 1;
    if (resid){
      out[ta*N + j] = __fadd_rn(resid[ta*N + j], a0);
      out[tb*N + j] = __fadd_rn(resid[tb*N + j], a1);
    } else {
      out[ta*N + j] = a0;
      out[tb*N + j] = a1;
    }
  }
}

// ---------------- attention scores: kt re-laid [d][mm], packed fma ----------------
__global__ __launch_bounds__(256) void attn_scores_k(const float* qkv, float* sc){
  __shared__ float kt[64][34];            // [d][mm], pad->2-way max
  int nh = blockIdx.x;
  int n  = nh / NHEAD, h = nh % NHEAD;
  int m0 = blockIdx.y * 32;
  int l  = threadIdx.x;
  for (int v = threadIdx.x; v < 32*64; v += 256){
    int mm = v >> 6, d = v & 63;
    kt[d][mm] = qkv[(size_t)((m0+mm)*2 + n)*QKVD + EMB + h*HD + d];
  }
  __syncthreads();
  f32x2 acc[16];
#pragma unroll
  for (int i = 0; i < 16; ++i) acc[i] = {0.f,0.f};
  const float* qrow = qkv + (size_t)(l*2 + n)*QKVD + h*HD;
  for (int d = 0; d < HD; ++d){
    float qv = qrow[d];
    f32x2 q2 = {qv, qv};
    const f32x2* kp = (const f32x2*)&kt[d][0];
#pragma unroll
    for (int i = 0; i < 16; ++i) acc[i] = pkfma(q2, kp[i], acc[i]);
  }
  float* srow = sc + ((size_t)nh*256 + l)*256 + m0;
#pragma unroll
  for (int i = 0; i < 16; ++i){
    srow[2*i]   = __fdiv_rn(acc[i].x, 8.0f);
    srow[2*i+1] = __fdiv_rn(acc[i].y, 8.0f);
  }
}

__global__ void softmax_rows_k(float* sc){
  int row = blockIdx.x*256 + threadIdx.x;
  if (row >= 24*256) return;
  float* p = sc + (size_t)row*256;
  float mx = p[0];
  for (int m = 1; m < 256; ++m) mx = fmaxf(mx, p[m]);
  for (int m = 0; m < 256; ++m) p[m] = xla_exp_f32(__fsub_rn(p[m], mx));
  float s = 0.0f;
  for (int m = 0; m < 256; ++m) s = __fadd_rn(s, p[m]);
  for (int m = 0; m < 256; ++m) p[m] = __fdiv_rn(p[m], s);
}

// 2 outputs (i, i+1) per thread, packed fma; chain over m ascending per output (exact)
__global__ void attn_ctx_k(const float* sc, const float* qkv, float* ctx){
  int idx = blockIdx.x*256 + threadIdx.x;     // t*384 + i/2
  int t = idx / 384, i2 = idx % 384;
  int i = i2*2;
  int l = t >> 1, n = t & 1, h = i >> 6;
  const float* arow = sc + ((size_t)(n*NHEAD + h)*256 + l)*256;
  f32x2 acc = {0.f,0.f};
  for (int m = 0; m < 256; ++m){
    float av = arow[m];
    f32x2 a2 = {av, av};
    f32x2 v2 = *(const f32x2*)&qkv[(size_t)(m*2 + n)*QKVD + 1536 + i];
    acc = pkfma(a2, v2, acc);
  }
  ctx[(size_t)t*EMB + i]     = acc.x;
  ctx[(size_t)t*EMB + i + 1] = acc.y;
}

__global__ void ln_rows_k(const float* in, const float* g, const float* b, float* out){
  int t = blockIdx.x*256 + threadIdx.x;
  if (t >= TOK) return;
  const float* p = in + (size_t)t*EMB;
  float s = 0.0f;
  for (int e = 0; e < EMB; ++e) s = __fadd_rn(s, p[e]);
  float mu = __fdiv_rn(s, 768.0f);
  float s2 = 0.0f;
  for (int e = 0; e < EMB; ++e){
    float d = __fsub_rn(p[e], mu);
    s2 = __fadd_rn(s2, __fmul_rn(d, d));
  }
  float var = __fdiv_rn(s2, 768.0f);
  float rs = __fdiv_rn(1.0f, __fsqrt_rn(__fadd_rn(var, 1e-5f)));
  for (int e = 0; e < EMB; ++e){
    float d = __fsub_rn(p[e], mu);
    out[(size_t)t*EMB + e] = __fadd_rn(__fmul_rn(__fmul_rn(d, rs), g[e]), b[e]);
  }
}

// final layernorm; m2 is TRANSPOSED [e][t]
__global__ void final_ln_rows_k(const float* h1, const float* m2T, const float* g, const float* b, float* out){
  int t = blockIdx.x*256 + threadIdx.x;
  if (t >= TOK) return;
  const float* p = h1 + (size_t)t*EMB;
  float s = 0.0f;
  for (int e = 0; e < EMB; ++e) s = __fadd_rn(s, __fadd_rn(p[e], m2T[(size_t)e*TOK + t]));
  float mu = __fdiv_rn(s, 768.0f);
  float s2 = 0.0f;
  for (int e = 0; e < EMB; ++e){
    float d = __fsub_rn(__fadd_rn(p[e], m2T[(size_t)e*TOK + t]), mu);
    s2 = __fadd_rn(s2, __fmul_rn(d, d));
  }
  float var = __fdiv_rn(s2, 768.0f);
  float rs = __fdiv_rn(1.0f, __fsqrt_rn(__fadd_rn(var, 1e-5f)));
  for (int e = 0; e < EMB; ++e){
    float d = __fsub_rn(__fadd_rn(p[e], m2T[(size_t)e*TOK + t]), mu);
    out[(size_t)t*EMB + e] = __fadd_rn(__fmul_rn(__fmul_rn(d, rs), g[e]), b[e]);
  }
}

// ---------------- qlinear (strict f32, packed fma) ----------------
__global__ void quantx_k(const float* val, const unsigned long long* xmax_slot, int Fin,
                         signed char* XqT){
  int idx = blockIdx.x*256 + threadIdx.x;
  if (idx >= TOK*Fin) return;
  int t = idx / Fin, i = idx % Fin;
  float xmax = (float)readSlot(xmax_slot);
  float u = __fmul_rn(__fdiv_rn(val[idx], xmax), 7.0f);
  XqT[(size_t)i*TOK + t] = (signed char)(int)rintf(u);
}

__global__ void quantxT_k(const float* valT, const unsigned long long* xmax_slot, int n,
                          signed char* XqT){
  int idx = blockIdx.x*256 + threadIdx.x;
  if (idx >= n) return;
  float xmax = (float)readSlot(xmax_slot);
  float u = __fmul_rn(__fdiv_rn(valT[idx], xmax), 7.0f);
  XqT[idx] = (signed char)(int)rintf(u);
}

__global__ void sumxb_k(const signed char* XqT, int NC, int* sumxb, unsigned long long* dmax_slot){
  int idx = blockIdx.x*256 + threadIdx.x;
  if (idx >= TOK*NC) return;
  int t = idx / NC, c = idx % NC;
  int n0 = 0, n1 = 0, n2 = 0;
  for (int s = 0; s < SUBA; ++s){
    int q = XqT[(size_t)(c*SUBA + s)*TOK + t];
    int a = q < 0 ? -q : q;
    int sg = (q > 0) - (q < 0);
    n0 += (a & 1) * sg; n1 += ((a >> 1) & 1) * sg; n2 += ((a >> 2) & 1) * sg;
  }
  sumxb[idx*3 + 0] = n0; sumxb[idx*3 + 1] = n1; sumxb[idx*3 + 2] = n2;
  float d0 = fabsf(__fmul_rn(0.55f, (float)n0));
  float d1 = fabsf(__fmul_rn(0.55f, (float)n1));
  float d2 = fabsf(__fmul_rn(0.55f, (float)n2));
  float m = fmaxf(d0, fmaxf(d1, d2));
  atomicMax(dmax_slot, (unsigned long long)__double_as_longlong((double)m));
}

// dqT layout: [c][z][t]
__global__ void dummyq_k(const int* sumxb, int NC, const unsigned long long* dmax_slot, float* dqT){
  int idx = blockIdx.x*256 + threadIdx.x;
  if (idx >= TOK*NC*3) return;
  int t = idx / (NC*3);
  int r = idx % (NC*3);
  int c = r / 3, z = r % 3;
  float dmax = (float)readSlot(dmax_slot);
  float step = __fdiv_rn(dmax, 31.0f);
  if (!(step > 0.0f)) step = 1.0f;
  float P = __fmul_rn(0.55f, (float)sumxb[idx]);
  dqT[((size_t)c*3 + z)*TOK + t] = __fmul_rn(rintf(__fdiv_rn(P, step)), step);
}

template<int OTILE>
__device__ __forceinline__ void qlin_stage(const signed char* XqT, const unsigned char* Wdec,
                                           const float* noise, int Fin, int c, int o0, int t0,
                                           signed char* xq, float (*cond)[SUBA][4]){
  const int tid = threadIdx.x;
  const uint32_t* src = (const uint32_t*)(XqT + (size_t)c*SUBA*TOK + t0);
  uint32_t* dst = (uint32_t*)xq;
  for (int j = tid; j < SUBA*64; j += 256){
    int s = j >> 6, dw = j & 63;
    dst[s*64 + dw] = src[s*128 + dw];
  }
  for (int v = tid; v < OTILE*SUBA*4; v += 256){
    int o = v >> 9;
    int r = v & 511;
    int s = r >> 2, k = r & 3;
    size_t i = (size_t)(o0+o)*Fin + c*SUBA + s;
    float bit = (float)((Wdec[i] >> k) & 1);
    float nz  = noise[i*4 + k];
    cond[o][s][k] = __fmul_rn(__fadd_rn(__fmul_rn(bit, 0.9f), 0.1f), __fadd_rn(1.0f, nz));
  }
}

// packed inner: acc2[o][z*2+(k>=2)] components (k&1); per-output chain s ascending — bit-exact
template<int OTILE>
__device__ __forceinline__ void qlin_acc_c(const signed char* xq, const float (*cond)[SUBA][4],
                                           f32x2 (*acc)[6]){
  const int tid = threadIdx.x;
#pragma unroll
  for (int o = 0; o < OTILE; ++o)
#pragma unroll
    for (int r = 0; r < 6; ++r) acc[o][r] = {0.f,0.f};
  for (int s = 0; s < SUBA; ++s){
    int q = xq[s*256 + tid];
    int a = q < 0 ? -q : q;
    int i0 = a & 1, i1 = (a >> 1) & 1, i2 = (a >> 2) & 1;
    if (q < 0){ i0 = -i0; i1 = -i1; i2 = -i2; }
    float f0 = (float)i0, f1 = (float)i1, f2 = (float)i2;
    f32x2 b0 = {f0, f0}, b1 = {f1, f1}, b2 = {f2, f2};
#pragma unroll
    for (int o = 0; o < OTILE; ++o){
      const f32x2* cp = (const f32x2*)&cond[o][s][0];
      f32x2 c01 = cp[0], c23 = cp[1];
      acc[o][0] = pkfma(b0, c01, acc[o][0]);
      acc[o][1] = pkfma(b0, c23, acc[o][1]);
      acc[o][2] = pkfma(b1, c01, acc[o][2]);
      acc[o][3] = pkfma(b1, c23, acc[o][3]);
      acc[o][4] = pkfma(b2, c01, acc[o][4]);
      acc[o][5] = pkfma(b2, c23, acc[o][5]);
    }
  }
}

// pass1: global max |partial| — c-range split across blockIdx.z (max is order-free)
template<int OTILE, int CCHUNK>
__global__ __launch_bounds__(256) void qlin_pass1_t(const signed char* XqT, const unsigned char* Wdec,
                                                    const float* noise, int Fin,
                                                    unsigned long long* ymax_slot){
  __shared__ signed char xq[SUBA*256];
  __shared__ float cond[OTILE][SUBA][4];
  __shared__ double red[256];
  const int o0 = blockIdx.x*OTILE;
  const int t0 = blockIdx.y*256;
  const int c0 = blockIdx.z*CCHUNK;
  f32x2 acc[OTILE][6];
  float lmax = 0.0f;
  for (int c = c0; c < c0 + CCHUNK; ++c){
    __syncthreads();
    qlin_stage<OTILE>(XqT, Wdec, noise, Fin, c, o0, t0, xq, cond);
    __syncthreads();
    qlin_acc_c<OTILE>(xq, cond, acc);
#pragma unroll
    for (int o = 0; o < OTILE; ++o)
#pragma unroll
      for (int r = 0; r < 6; ++r){
        lmax = fmaxf(lmax, fabsf(acc[o][r].x));
        lmax = fmaxf(lmax, fabsf(acc[o][r].y));
      }
  }
  blockMaxAtomic((double)lmax, ymax_slot, red);
}

template<int OTILE>
__global__ __launch_bounds__(256) void qlin_pass2_t(const signed char* XqT, const unsigned char* Wdec,
                                                    const float* noise, const float* dqT, const float* bias,
                                                    int Fin, int NC,
                                                    const unsigned long long* ymax_slot,
                                                    const unsigned long long* xmax_slot,
                                                    const unsigned long long* wmax_slot,
                                                    float* outT){
  __shared__ signed char xq[SUBA*256];
  __shared__ float cond[OTILE][SUBA][4];
  const int o0 = blockIdx.x*OTILE;
  const int t0 = blockIdx.y*256;
  const int t  = t0 + threadIdx.x;
  float ymax = (float)readSlot(ymax_slot);
  float step = __fdiv_rn(ymax, 31.0f);
  if (!(step > 0.0f)) step = 1.0f;
  f32x2 acc[OTILE][6];
  float netsum[OTILE][12];
#pragma unroll
  for (int o = 0; o < OTILE; ++o)
#pragma unroll
    for (int r = 0; r < 12; ++r) netsum[o][r] = 0.0f;
  for (int c = 0; c < NC; ++c){
    __syncthreads();
    qlin_stage<OTILE>(XqT, Wdec, noise, Fin, c, o0, t0, xq, cond);
    __syncthreads();
    qlin_acc_c<OTILE>(xq, cond, acc);
    float dqv[3];
#pragma unroll
    for (int z = 0; z < 3; ++z) dqv[z] = dqT[((size_t)c*3 + z)*TOK + t];
#pragma unroll
    for (int o = 0; o < OTILE; ++o)
#pragma unroll
      for (int z = 0; z < 3; ++z)
#pragma unroll
        for (int k = 0; k < 4; ++k){
          f32x2 av2 = acc[o][z*2 + (k >> 1)];
          float av = (k & 1) ? av2.y : av2.x;
          float pq  = __fmul_rn(rintf(__fdiv_rn(av, step)), step);
          float net = __fsub_rn(pq, dqv[z]);
          netsum[o][z*4+k] = __fadd_rn(netsum[o][z*4+k], net);
        }
  }
  float xmax = (float)readSlot(xmax_slot);
  float wmax = (float)readSlot(wmax_slot);
  float A = __fdiv_rn(xmax, 7.0f);
  float B = __fdiv_rn(__fmul_rn(2.0f, wmax), 13.5f);
#pragma unroll
  for (int o = 0; o < OTILE; ++o){
    float tot = 0.0f;
#pragma unroll
    for (int z = 0; z < 3; ++z)
#pragma unroll
      for (int k = 0; k < 4; ++k)
        tot = __fadd_rn(tot, __fmul_rn(netsum[o][z*4+k], (float)(1 << (z + k))));
    float outv = __fadd_rn(__fmul_rn(__fmul_rn(tot, A), B), bias[o0+o]);
    outT[(size_t)(o0+o)*TOK + t] = outv;
  }
}

__global__ void gelu_absmax_k(const float* m1, int n, float* x2, unsigned long long* xmax_slot){
  __shared__ double red[256];
  double m = 0.0;
  for (int i = blockIdx.x*256 + threadIdx.x; i < n; i += gridDim.x*256){
    float v = m1[i];
    float t1 = __fdiv_rn(v, 1.4142135623730951f);
    float e = xla_erf_f32(t1);
    float s = __fadd_rn(e, 1.0f);
    float g = __fdiv_rn(__fmul_rn(v, s), 2.0f);
    x2[i] = g;
    double a = fabs((double)g); if (a > m) m = a;
  }
  blockMaxAtomic(m, xmax_slot, red);
}

// ---------------- host launch ----------------
extern "C" void kernel_launch(void* const* d_in, const int* in_sizes, int n_in,
                              void* d_out, int out_size, void* d_ws, size_t ws_size,
                              hipStream_t stream){
  if (ws_size < WS_NEEDED) return;
  const float* x      = (const float*)d_in[0];
  const float* in_w   = (const float*)d_in[1];
  const float* in_b   = (const float*)d_in[2];
  const float* out_w  = (const float*)d_in[3];
  const float* out_b  = (const float*)d_in[4];
  const float* ln1_g  = (const float*)d_in[5];
  const float* ln1_b  = (const float*)d_in[6];
  const float* W1     = (const float*)d_in[7];
  const float* b1     = (const float*)d_in[8];
  const float* W2     = (const float*)d_in[9];
  const float* b2     = (const float*)d_in[10];
  const float* ln2_g  = (const float*)d_in[11];
  const float* ln2_b  = (const float*)d_in[12];

  char* ws = (char*)d_ws;
  float* qkv    = (float*)(ws + OFF_QKV);
  float* scores = (float*)(ws + OFF_SCORES);
  float* ctx    = (float*)(ws + OFF_CTX);
  float* h1pre  = (float*)(ws + OFF_H1PRE);
  float* h1     = (float*)(ws + OFF_H1);
  float* m1     = (float*)(ws + OFF_M1);     // [MLPD][TOK]
  float* x2     = (float*)(ws + OFF_X2);     // [MLPD][TOK]
  float* m2     = (float*)(ws + OFF_M2);     // [EMB][TOK]
  float* dq1    = (float*)(ws + OFF_DQ1);    // [6][3][TOK]
  float* dq2    = (float*)(ws + OFF_DQ2);    // [24][3][TOK]
  unsigned long long* scal = (unsigned long long*)(ws + OFF_SCAL);
  float* noise1  = (float*)(ws + OFF_NOISE1);
  float* noise2  = (float*)(ws + OFF_NOISE2);
  int*   sumxb1  = (int*)(ws + OFF_SUMXB1);
  int*   sumxb2  = (int*)(ws + OFF_SUMXB2);
  unsigned char* wdec1 = (unsigned char*)(ws + OFF_WDEC1);
  unsigned char* wdec2 = (unsigned char*)(ws + OFF_WDEC2);
  signed char* xqt1 = (signed char*)(ws + OFF_XQT1);
  signed char* xqt2 = (signed char*)(ws + OFF_XQT2);

  hipMemsetAsync(scal, 0, 64, stream);

  absmax_f32_k<<<1024,256,0,stream>>>(W1, MLPD*EMB, scal+0);
  absmax_f32_k<<<1024,256,0,stream>>>(W2, EMB*MLPD, scal+1);

  noise_gen_k<<<36864,256,0,stream>>>(0u, 1u, 9437184u, noise1);
  noise_gen_k<<<36864,256,0,stream>>>(0u, 2u, 9437184u, noise2);
  wdec_gen_k<<<9216,256,0,stream>>>(W1, MLPD*EMB, scal+0, wdec1);
  wdec_gen_k<<<9216,256,0,stream>>>(W2, EMB*MLPD, scal+1, wdec2);

  // attention (f32, XLA-faithful)
  gemm8_k<<<dim3(9,64),256,0,stream>>>(x, in_w, in_b, nullptr, qkv, QKVD, EMB);
  attn_scores_k<<<dim3(24,8),256,0,stream>>>(qkv, scores);
  softmax_rows_k<<<24,256,0,stream>>>(scores);
  attn_ctx_k<<<768,256,0,stream>>>(scores, qkv, ctx);
  gemm8_k<<<dim3(3,64),256,0,stream>>>(ctx, out_w, out_b, x, h1pre, EMB, EMB);
  ln_rows_k<<<2,256,0,stream>>>(h1pre, ln1_g, ln1_b, h1);

  // qlinear 1 (768 -> 3072)
  absmax_f32_k<<<1024,256,0,stream>>>(h1, TOK*EMB, scal+2);
  quantx_k<<<(TOK*EMB+255)/256,256,0,stream>>>(h1, scal+2, EMB, xqt1);
  sumxb_k<<<(TOK*6+255)/256,256,0,stream>>>(xqt1, 6, sumxb1, scal+4);
  dummyq_k<<<(TOK*6*3+255)/256,256,0,stream>>>(sumxb1, 6, scal+4, dq1);
  qlin_pass1_t<8,3><<<dim3(MLPD/8,2,2),256,0,stream>>>(xqt1, wdec1, noise1, EMB, scal+3);
  qlin_pass2_t<4><<<dim3(MLPD/4,2),256,0,stream>>>(xqt1, wdec1, noise1, dq1, b1,
                                                   EMB, 6, scal+3, scal+2, scal+0, m1);

  // gelu + qlinear 2 (3072 -> 768)
  gelu_absmax_k<<<6144,256,0,stream>>>(m1, TOK*MLPD, x2, scal+5);
  quantxT_k<<<(TOK*MLPD+255)/256,256,0,stream>>>(x2, scal+5, TOK*MLPD, xqt2);
  sumxb_k<<<(TOK*24+255)/256,256,0,stream>>>(xqt2, 24, sumxb2, scal+7);
  dummyq_k<<<(TOK*24*3+255)/256,256,0,stream>>>(sumxb2, 24, scal+7, dq2);
  qlin_pass1_t<4,6><<<dim3(EMB/4,2,4),256,0,stream>>>(xqt2, wdec2, noise2, MLPD, scal+6);
  qlin_pass2_t<4><<<dim3(EMB/4,2),256,0,stream>>>(xqt2, wdec2, noise2, dq2, b2,
                                                  MLPD, 24, scal+6, scal+5, scal+1, m2);

  // final residual + layernorm -> f32 out
  final_ln_rows_k<<<2,256,0,stream>>>(h1, m2, ln2_g, ln2_b, (float*)d_out);
}